// Round 5
// baseline (6627.685 us; speedup 1.0000x reference)
//
#include <hip/hip_runtime.h>
#include <math.h>

#define BATCH 8
#define NPTS 8192
#define CFEAT 64
#define NC 2048           // S centers
#define KNN 32
#define NSCOL (NC*KNN)    // 65536 columns per batch
#define R2 0.0625f        // radius^2
#define GN_EPS 1e-5f

// ---- workspace layout (bytes) ----
#define OFF_CIDX  0ull
#define OFF_NIDX  65536ull
#define OFF_CENT  2162688ull
#define OFF_STATS 2359296ull
#define OFF_WT    2361344ull
#define OFF_XALL  4194304ull
#define OFF_Y     23068672ull
#define WS_NEEDED (OFF_Y + 8ull*64*NSCOL*4ull)   // 150 MiB

static __device__ __forceinline__ unsigned f2bf(float f) {
    unsigned u = __float_as_uint(f);
    return (u + 0x7fffu + ((u >> 16) & 1u)) >> 16;   // RNE, finite inputs
}

// =====================================================================
__global__ void prep_kernel(const float* __restrict__ w0, const float* __restrict__ w1,
                            const float* __restrict__ w2, float* __restrict__ stats,
                            float* __restrict__ wt)
{
    const int t = blockIdx.x * 256 + threadIdx.x;
    if (t < 384) stats[t] = 0.f;
    if (t < 64 * 67) { int o = t / 67, i = t - o * 67; wt[i * 64 + o] = w0[t]; }
    if (t < 64 * 64) { int o = t >> 6, i = t & 63;     wt[4288 + i * 64 + o] = w1[t]; }
    if (t < 128 * 64){ int o = t >> 6, i = t & 63;     wt[8384 + i * 128 + o] = w2[t]; }
}

// =====================================================================
__global__ __launch_bounds__(256) void build_xall(const float* __restrict__ coords,
                                                  const float* __restrict__ feats,
                                                  float* __restrict__ xall)
{
    const int tid = blockIdx.x * 256 + threadIdx.x;   // b*NPTS + p
    const int b = tid >> 13, p = tid & (NPTS - 1);
    const float* cb = coords + (size_t)b * 3 * NPTS;
    const float* fb = feats + (size_t)b * CFEAT * NPTS;
    float* xp = xall + (size_t)tid * 68;
    xp[0] = cb[p]; xp[1] = cb[NPTS + p]; xp[2] = cb[2 * NPTS + p];
#pragma unroll
    for (int c = 0; c < CFEAT; ++c) xp[3 + c] = fb[c * NPTS + p];
    xp[67] = 0.f;
}

// =====================================================================
// FPS v2: 1 block/batch, 512 threads, 16 pts/thread in VGPRs.
// Coords staged in dynamic LDS (98 KB) -> coords[cur] is a broadcast
// ds_read (no owner-broadcast step). Double-buffered per-wave packs ->
// ONE __syncthreads per iteration; every thread redundantly reduces
// the 8 packs (no serial t==0 step, no second barrier).
// No-contract fp32 matches numpy ((dx*dx+dy*dy)+dz*dz) bitwise.
// =====================================================================
__global__ __launch_bounds__(512) void fps_kernel(const float* __restrict__ coords,
                                                  int* __restrict__ cidx)
{
    extern __shared__ float smem[];
    float* sx = smem;                 // [NPTS]
    float* sy = smem + NPTS;          // [NPTS]
    float* sz = smem + 2 * NPTS;      // [NPTS]
    unsigned long long* wpack = (unsigned long long*)(smem + 3 * NPTS);  // [2][8]

    const int b = blockIdx.x;
    const int t = threadIdx.x;
    const float* cb = coords + (size_t)b * 3 * NPTS;

    float X[16], Y[16], Z[16], mind[16];
#pragma unroll
    for (int j = 0; j < 16; ++j) {
        int p = t + j * 512;
        X[j] = cb[p];
        Y[j] = cb[NPTS + p];
        Z[j] = cb[2 * NPTS + p];
        sx[p] = X[j]; sy[p] = Y[j]; sz[p] = Z[j];
        mind[j] = 1e10f;
    }
    if (t == 0) cidx[b * NC] = 0;
    __syncthreads();

    int cur = 0;
    for (int it = 1; it < NC; ++it) {
        const float lx = sx[cur], ly = sy[cur], lz = sz[cur];  // broadcast reads
        float bv = -1.0f; int bi = 0;
#pragma unroll
        for (int j = 0; j < 16; ++j) {
            float dx = __fsub_rn(X[j], lx);
            float dy = __fsub_rn(Y[j], ly);
            float dz = __fsub_rn(Z[j], lz);
            float d  = __fadd_rn(__fadd_rn(__fmul_rn(dx, dx), __fmul_rn(dy, dy)),
                                 __fmul_rn(dz, dz));
            float nm = fminf(mind[j], d);
            mind[j] = nm;
            if (nm > bv) { bv = nm; bi = t + j * 512; }   // strict >: lowest idx
        }
        unsigned long long pack = ((unsigned long long)__float_as_uint(bv) << 32)
                                | (unsigned long long)(unsigned)(NPTS - 1 - bi);
#pragma unroll
        for (int o = 32; o > 0; o >>= 1) {
            unsigned long long other = __shfl_xor(pack, o);
            if (other > pack) pack = other;
        }
        unsigned long long* wp = wpack + (it & 1) * 8;     // double buffer
        if ((t & 63) == 0) wp[t >> 6] = pack;
        __syncthreads();
        unsigned long long best = wp[0];
#pragma unroll
        for (int w = 1; w < 8; ++w) {
            unsigned long long v = wp[w];
            if (v > best) best = v;
        }
        cur = NPTS - 1 - (int)(best & 0xffffffffu);
        if (t == 0) cidx[b * NC + it] = cur;
    }
}

// =====================================================================
// Ball query -> nidx + centers. EXPANDED d2 form (cn+pn)-2*cp, no fma.
// =====================================================================
__global__ __launch_bounds__(256) void bq_kernel(const float* __restrict__ coords,
                                                 const int* __restrict__ cidx,
                                                 int* __restrict__ nidx,
                                                 float* __restrict__ centers)
{
    const int s = blockIdx.x, b = blockIdx.y, t = threadIdx.x;
    __shared__ int s_idx[KNN];
    __shared__ int s_pref[9];
    __shared__ float s_c[3];
    __shared__ float s_cn;
    const float* cb = coords + (size_t)b * 3 * NPTS;
    if (t == 0) {
        int ci = cidx[b * NC + s];
        float cx = cb[ci], cy = cb[NPTS + ci], cz = cb[2 * NPTS + ci];
        s_c[0] = cx; s_c[1] = cy; s_c[2] = cz;
        s_cn = __fadd_rn(__fadd_rn(__fmul_rn(cx, cx), __fmul_rn(cy, cy)),
                         __fmul_rn(cz, cz));
    }
    __syncthreads();
    const float cx = s_c[0], cy = s_c[1], cz = s_c[2], cn = s_cn;
    const int base = t * 32;
    int cnt = 0;
    for (int j = 0; j < 32; ++j) {
        int p = base + j;
        float x = cb[p], y = cb[NPTS + p], z = cb[2 * NPTS + p];
        float pn = __fadd_rn(__fadd_rn(__fmul_rn(x, x), __fmul_rn(y, y)), __fmul_rn(z, z));
        float cp = __fadd_rn(__fadd_rn(__fmul_rn(cx, x), __fmul_rn(cy, y)), __fmul_rn(cz, z));
        float d2 = __fsub_rn(__fadd_rn(cn, pn), __fmul_rn(2.0f, cp));
        if (d2 < R2) ++cnt;
    }
    const int lane = t & 63, wid = t >> 6;
    int incl = cnt;
    for (int o = 1; o < 64; o <<= 1) {
        int v = __shfl_up(incl, o);
        if (lane >= o) incl += v;
    }
    if (lane == 63) s_pref[wid] = incl;
    __syncthreads();
    int ex = incl - cnt;
    for (int w = 0; w < wid; ++w) ex += s_pref[w];
    if (t == 255) s_pref[8] = ex + cnt;
    if (ex < KNN && cnt > 0) {
        int slot = ex;
        for (int j = 0; j < 32 && slot < KNN; ++j) {
            int p = base + j;
            float x = cb[p], y = cb[NPTS + p], z = cb[2 * NPTS + p];
            float pn = __fadd_rn(__fadd_rn(__fmul_rn(x, x), __fmul_rn(y, y)), __fmul_rn(z, z));
            float cp = __fadd_rn(__fadd_rn(__fmul_rn(cx, x), __fmul_rn(cy, y)), __fmul_rn(cz, z));
            float d2 = __fsub_rn(__fadd_rn(cn, pn), __fmul_rn(2.0f, cp));
            if (d2 < R2) { s_idx[slot] = p; ++slot; }
        }
    }
    __syncthreads();
    const int total = s_pref[8];
    if (t < KNN) {
        int v = (total == 0) ? 0 : ((t < total) ? s_idx[t] : s_idx[0]);
        nidx[(b * NC + s) * KNN + t] = v;
    }
    if (t < 3) centers[(b * NC + s) * 3 + t] = s_c[t];
}

// =====================================================================
// Layer 1 (fused gather): 2 output-chunks of 32.
// =====================================================================
__global__ __launch_bounds__(256) void l1_kernel(const float* __restrict__ xall,
                                                 const int* __restrict__ nidx,
                                                 const float* __restrict__ centers,
                                                 const float* __restrict__ wt,
                                                 const float* __restrict__ b0,
                                                 float* __restrict__ Y,
                                                 float* __restrict__ stats)
{
    __shared__ float sw[68 * 64];
    __shared__ float s_sum[8], s_sq[8];
    const int b = blockIdx.y, t = threadIdx.x;
    for (int i = t; i < 67 * 64; i += 256) sw[i] = wt[i];
    if (t < 64) sw[67 * 64 + t] = b0[t];
    if (t < 8) { s_sum[t] = 0.f; s_sq[t] = 0.f; }
    __syncthreads();
    const int n = blockIdx.x * 256 + t;
    const int s = n >> 5, k = n & 31;
    const int p = nidx[(b * NC + s) * KNN + k];
    const float4* xp4 = (const float4*)(xall + (size_t)(b * NPTS + p) * 68);
    float xf[68];
#pragma unroll
    for (int q = 0; q < 17; ++q) {
        float4 v = xp4[q];
        xf[4 * q] = v.x; xf[4 * q + 1] = v.y; xf[4 * q + 2] = v.z; xf[4 * q + 3] = v.w;
    }
    const float* cc = centers + (size_t)(b * NC + s) * 3;
    xf[0] -= cc[0]; xf[1] -= cc[1]; xf[2] -= cc[2];
    float* yb = Y + (size_t)b * 64 * NSCOL + n;
#pragma unroll 1
    for (int c = 0; c < 2; ++c) {
        float acc[32];
#pragma unroll
        for (int o = 0; o < 32; ++o) acc[o] = sw[67 * 64 + c * 32 + o];
#pragma unroll
        for (int i = 0; i < 67; ++i) {
#pragma unroll
            for (int o = 0; o < 32; ++o)
                acc[o] = fmaf(sw[i * 64 + c * 32 + o], xf[i], acc[o]);
        }
#pragma unroll
        for (int o = 0; o < 32; ++o) yb[(size_t)(c * 32 + o) * NSCOL] = acc[o];
#pragma unroll
        for (int g = 0; g < 4; ++g) {
            float sv = 0.f, sq = 0.f;
#pragma unroll
            for (int j = 0; j < 8; ++j) { float vv = acc[g * 8 + j]; sv += vv; sq = fmaf(vv, vv, sq); }
#pragma unroll
            for (int o = 32; o > 0; o >>= 1) { sv += __shfl_xor(sv, o); sq += __shfl_xor(sq, o); }
            if ((t & 63) == 0) { atomicAdd(&s_sum[c * 4 + g], sv); atomicAdd(&s_sq[c * 4 + g], sq); }
        }
    }
    __syncthreads();
    if (t < 8) {
        atomicAdd(&stats[(b * 8 + t) * 2 + 0], s_sum[t]);
        atomicAdd(&stats[(b * 8 + t) * 2 + 1], s_sq[t]);
    }
}

// =====================================================================
// Layer 2: in-place, 2 output-chunks of 32.
// =====================================================================
__global__ __launch_bounds__(256) void l2_kernel(const float* __restrict__ wt1,
                                                 const float* __restrict__ b1,
                                                 const float* __restrict__ g0,
                                                 const float* __restrict__ be0,
                                                 const float* __restrict__ stats_in,
                                                 float* __restrict__ stats_out,
                                                 float* __restrict__ Y)
{
    __shared__ float sw[65 * 64];
    __shared__ float sA[64], sB[64];
    __shared__ float s_sum[8], s_sq[8];
    const int b = blockIdx.y, t = threadIdx.x;
    for (int i = t; i < 64 * 64; i += 256) sw[i] = wt1[i];
    if (t < 64) {
        sw[64 * 64 + t] = b1[t];
        const int g = t >> 3;
        const float inv = 1.0f / (8.0f * NSCOL);
        float mu = stats_in[(b * 8 + g) * 2 + 0] * inv;
        float var = stats_in[(b * 8 + g) * 2 + 1] * inv - mu * mu;
        float A = (1.0f / sqrtf(var + GN_EPS)) * g0[t];
        sA[t] = A; sB[t] = be0[t] - mu * A;
    }
    if (t < 8) { s_sum[t] = 0.f; s_sq[t] = 0.f; }
    __syncthreads();
    const int n = blockIdx.x * 256 + t;
    float* yb = Y + (size_t)b * 64 * NSCOL + n;
    float xn[64];
#pragma unroll
    for (int i = 0; i < 64; ++i) {
        float raw = yb[(size_t)i * NSCOL];
        float v = fmaf(raw, sA[i], sB[i]);
        xn[i] = v * __builtin_amdgcn_rcpf(1.0f + __expf(-v));
    }
#pragma unroll 1
    for (int c = 0; c < 2; ++c) {
        float acc[32];
#pragma unroll
        for (int o = 0; o < 32; ++o) acc[o] = sw[64 * 64 + c * 32 + o];
#pragma unroll
        for (int i = 0; i < 64; ++i) {
#pragma unroll
            for (int o = 0; o < 32; ++o)
                acc[o] = fmaf(sw[i * 64 + c * 32 + o], xn[i], acc[o]);
        }
#pragma unroll
        for (int o = 0; o < 32; ++o) yb[(size_t)(c * 32 + o) * NSCOL] = acc[o];
#pragma unroll
        for (int g = 0; g < 4; ++g) {
            float sv = 0.f, sq = 0.f;
#pragma unroll
            for (int j = 0; j < 8; ++j) { float vv = acc[g * 8 + j]; sv += vv; sq = fmaf(vv, vv, sq); }
#pragma unroll
            for (int o = 32; o > 0; o >>= 1) { sv += __shfl_xor(sv, o); sq += __shfl_xor(sq, o); }
            if ((t & 63) == 0) { atomicAdd(&s_sum[c * 4 + g], sv); atomicAdd(&s_sq[c * 4 + g], sq); }
        }
    }
    __syncthreads();
    if (t < 8) {
        atomicAdd(&stats_out[(b * 8 + t) * 2 + 0], s_sum[t]);
        atomicAdd(&stats_out[(b * 8 + t) * 2 + 1], s_sq[t]);
    }
}

// =====================================================================
// Layer 3 v2: GN2+SiLU output stored as bf16 PAIRS in 32 uints (halves
// the dominant live array -> no spill; __launch_bounds__(256,3) caps
// VGPR ~170). 4 output-chunks of 32; stats on fp32 acc; bf16-pack
// output in place.
// =====================================================================
__global__ __launch_bounds__(256, 3) void l3_kernel(const float* __restrict__ wt2,
                                                    const float* __restrict__ b2,
                                                    const float* __restrict__ g1,
                                                    const float* __restrict__ be1,
                                                    const float* __restrict__ stats_in,
                                                    float* __restrict__ stats_out,
                                                    float* __restrict__ Y)
{
    __shared__ float sw[64 * 128 + 128];
    __shared__ float sA[64], sB[64];
    __shared__ float s_sum[8], s_sq[8];
    const int b = blockIdx.y, t = threadIdx.x;
    for (int i = t; i < 64 * 128; i += 256) sw[i] = wt2[i];
    if (t < 128) sw[64 * 128 + t] = b2[t];
    if (t < 64) {
        const int g = t >> 3;
        const float inv = 1.0f / (8.0f * NSCOL);
        float mu = stats_in[(b * 8 + g) * 2 + 0] * inv;
        float var = stats_in[(b * 8 + g) * 2 + 1] * inv - mu * mu;
        float A = (1.0f / sqrtf(var + GN_EPS)) * g1[t];
        sA[t] = A; sB[t] = be1[t] - mu * A;
    }
    if (t < 8) { s_sum[t] = 0.f; s_sq[t] = 0.f; }
    __syncthreads();
    const int n = blockIdx.x * 256 + t;
    float* yb = Y + (size_t)b * 64 * NSCOL + n;
    // GN+SiLU -> bf16 pairs (32 uints instead of 64 floats)
    unsigned xnp[32];
#pragma unroll
    for (int i = 0; i < 32; ++i) {
        float r0 = yb[(size_t)(2 * i) * NSCOL];
        float r1 = yb[(size_t)(2 * i + 1) * NSCOL];
        float v0 = fmaf(r0, sA[2 * i], sB[2 * i]);
        v0 = v0 * __builtin_amdgcn_rcpf(1.0f + __expf(-v0));
        float v1 = fmaf(r1, sA[2 * i + 1], sB[2 * i + 1]);
        v1 = v1 * __builtin_amdgcn_rcpf(1.0f + __expf(-v1));
        xnp[i] = f2bf(v0) | (f2bf(v1) << 16);
    }
    unsigned* yu = (unsigned*)yb;
#pragma unroll 1
    for (int c = 0; c < 4; ++c) {                     // 32 outputs per chunk
        float acc[32];
#pragma unroll
        for (int o = 0; o < 32; ++o) acc[o] = sw[64 * 128 + c * 32 + o];
#pragma unroll
        for (int i = 0; i < 64; ++i) {
            float xv = __uint_as_float((i & 1) ? (xnp[i >> 1] & 0xffff0000u)
                                               : (xnp[i >> 1] << 16));
#pragma unroll
            for (int o = 0; o < 32; ++o)
                acc[o] = fmaf(sw[i * 128 + c * 32 + o], xv, acc[o]);
        }
#pragma unroll
        for (int g = 0; g < 2; ++g) {                 // groups 2c+g (16 ch)
            float sv = 0.f, sq = 0.f;
#pragma unroll
            for (int j = 0; j < 16; ++j) { float vv = acc[g * 16 + j]; sv += vv; sq = fmaf(vv, vv, sq); }
#pragma unroll
            for (int o = 32; o > 0; o >>= 1) { sv += __shfl_xor(sv, o); sq += __shfl_xor(sq, o); }
            if ((t & 63) == 0) { atomicAdd(&s_sum[c * 2 + g], sv); atomicAdd(&s_sq[c * 2 + g], sq); }
        }
#pragma unroll
        for (int j = 0; j < 16; ++j) {                // pack uint rows c*16+j
            unsigned u = f2bf(acc[2 * j]) | (f2bf(acc[2 * j + 1]) << 16);
            yu[(size_t)(c * 16 + j) * NSCOL] = u;
        }
    }
    __syncthreads();
    if (t < 8) {
        atomicAdd(&stats_out[(b * 8 + t) * 2 + 0], s_sum[t]);
        atomicAdd(&stats_out[(b * 8 + t) * 2 + 1], s_sq[t]);
    }
}

// =====================================================================
// Finalize: GN3 + SiLU + max over K. Thread per (b, channel-PAIR, s).
// =====================================================================
__global__ __launch_bounds__(256) void fin_kernel(const unsigned* __restrict__ Yu,
                                                  const float* __restrict__ g2,
                                                  const float* __restrict__ be2,
                                                  const float* __restrict__ stats,
                                                  float* __restrict__ out)
{
    const int tid = blockIdx.x * 256 + threadIdx.x;
    const int s = tid & (NC - 1);
    const int cp = (tid >> 11) & 63;
    const int b = tid >> 17;
    const int g = cp >> 3;
    const float inv = 1.0f / (16.0f * NSCOL);
    float mu = stats[(b * 8 + g) * 2 + 0] * inv;
    float var = stats[(b * 8 + g) * 2 + 1] * inv - mu * mu;
    float rs = 1.0f / sqrtf(var + GN_EPS);
    const int c0 = cp * 2, c1 = c0 + 1;
    float A0 = rs * g2[c0], B0 = be2[c0] - mu * A0;
    float A1 = rs * g2[c1], B1 = be2[c1] - mu * A1;
    const unsigned* yb = Yu + (size_t)(b * 64 + cp) * NSCOL + s * KNN;
    float m0 = -INFINITY, m1 = -INFINITY;
#pragma unroll
    for (int q = 0; q < 8; ++q) {
        uint4 v = ((const uint4*)yb)[q];
        unsigned uu[4] = {v.x, v.y, v.z, v.w};
#pragma unroll
        for (int r = 0; r < 4; ++r) {
            float f0 = __uint_as_float(uu[r] << 16);
            float f1 = __uint_as_float(uu[r] & 0xffff0000u);
            float v0 = fmaf(f0, A0, B0);
            v0 = v0 * __builtin_amdgcn_rcpf(1.0f + __expf(-v0));
            m0 = fmaxf(m0, v0);
            float v1 = fmaf(f1, A1, B1);
            v1 = v1 * __builtin_amdgcn_rcpf(1.0f + __expf(-v1));
            m1 = fmaxf(m1, v1);
        }
    }
    out[(size_t)(b * 128 + c0) * NC + s] = m0;
    out[(size_t)(b * 128 + c1) * NC + s] = m1;
}

// =====================================================================
extern "C" void kernel_launch(void* const* d_in, const int* in_sizes, int n_in,
                              void* d_out, int out_size, void* d_ws, size_t ws_size,
                              hipStream_t stream)
{
    if (ws_size < WS_NEEDED) return;

    const float* coords = (const float*)d_in[0];
    const float* feats  = (const float*)d_in[1];
    const float* w0  = (const float*)d_in[2];
    const float* b0  = (const float*)d_in[3];
    const float* g0  = (const float*)d_in[4];
    const float* be0 = (const float*)d_in[5];
    const float* w1  = (const float*)d_in[6];
    const float* b1  = (const float*)d_in[7];
    const float* g1  = (const float*)d_in[8];
    const float* be1 = (const float*)d_in[9];
    const float* w2  = (const float*)d_in[10];
    const float* b2  = (const float*)d_in[11];
    const float* g2  = (const float*)d_in[12];
    const float* be2 = (const float*)d_in[13];
    float* out = (float*)d_out;

    char* ws = (char*)d_ws;
    int*   cidx    = (int*)(ws + OFF_CIDX);
    int*   nidx    = (int*)(ws + OFF_NIDX);
    float* centers = (float*)(ws + OFF_CENT);
    float* stats   = (float*)(ws + OFF_STATS);
    float* wt      = (float*)(ws + OFF_WT);
    float* xall    = (float*)(ws + OFF_XALL);
    float* Ybuf    = (float*)(ws + OFF_Y);

    prep_kernel<<<32, 256, 0, stream>>>(w0, w1, w2, stats, wt);
    build_xall<<<(BATCH * NPTS) / 256, 256, 0, stream>>>(coords, feats, xall);
    // dynamic LDS: 3*NPTS floats (coords) + 16 u64 packs = 98304 + 128 B
    fps_kernel<<<BATCH, 512, 3 * NPTS * 4 + 128, stream>>>(coords, cidx);
    bq_kernel<<<dim3(NC, BATCH), 256, 0, stream>>>(coords, cidx, nidx, centers);
    l1_kernel<<<dim3(NSCOL / 256, BATCH), 256, 0, stream>>>(
        xall, nidx, centers, wt, b0, Ybuf, stats);
    l2_kernel<<<dim3(NSCOL / 256, BATCH), 256, 0, stream>>>(
        wt + 4288, b1, g0, be0, stats, stats + 128, Ybuf);
    l3_kernel<<<dim3(NSCOL / 256, BATCH), 256, 0, stream>>>(
        wt + 8384, b2, g1, be1, stats + 128, stats + 256, Ybuf);
    fin_kernel<<<(BATCH * 64 * NC) / 256, 256, 0, stream>>>(
        (const unsigned*)Ybuf, g2, be2, stats + 256, out);
    (void)in_sizes; (void)n_in; (void)out_size;
}

// Round 6
// 3092.175 us; speedup vs baseline: 2.1434x; 2.1434x over previous
//
#include <hip/hip_runtime.h>
#include <math.h>

#define BATCH 8
#define NPTS 8192
#define CFEAT 64
#define NC 2048           // S centers
#define KNN 32
#define NSCOL (NC*KNN)    // 65536 columns per batch
#define R2 0.0625f        // radius^2
#define GN_EPS 1e-5f
#define SBINS 32          // stat partial bins (cuts atomic contention 32x)

// ---- workspace layout (bytes) ----
#define OFF_CIDX   0ull
#define OFF_NIDX   65536ull
#define OFF_CENT   2162688ull
#define OFF_STATSP 2359296ull            // 3 layers x 32 bins x 128 fl = 49152 B
#define OFF_STATSF 2408448ull            // 3 x 128 fl = 1536 B
#define OFF_WT     2410496ull            // 16576 fl = 66304 B
#define OFF_XALL   4194304ull            // 17,825,792 B
#define OFF_Y      23068672ull           // 134,217,728 B
#define WS_NEEDED  (OFF_Y + 8ull*64*NSCOL*4ull)   // 150 MiB

static __device__ __forceinline__ unsigned f2bf(float f) {
    unsigned u = __float_as_uint(f);
    return (u + 0x7fffu + ((u >> 16) & 1u)) >> 16;   // RNE, finite inputs
}

// =====================================================================
// prep: zero stat partials/finals; transpose weights to [i][o] layout.
// grid 48x256 = 12288 threads.
// =====================================================================
__global__ void prep_kernel(const float* __restrict__ w0, const float* __restrict__ w1,
                            const float* __restrict__ w2, float* __restrict__ statsP,
                            float* __restrict__ statsF, float* __restrict__ wt)
{
    const int t = blockIdx.x * 256 + threadIdx.x;
    if (t < 3 * SBINS * 128) statsP[t] = 0.f;
    if (t < 384) statsF[t] = 0.f;
    if (t < 64 * 67) { int o = t / 67, i = t - o * 67; wt[i * 64 + o] = w0[t]; }
    if (t < 64 * 64) { int o = t >> 6, i = t & 63;     wt[4288 + i * 64 + o] = w1[t]; }
    if (t < 128 * 64){ int o = t >> 6, i = t & 63;     wt[8384 + i * 128 + o] = w2[t]; }
}

// =====================================================================
// reduce 32 bins of one layer's stat partials -> final [128]
// =====================================================================
__global__ void reduce_stats(const float* __restrict__ statsPL, float* __restrict__ statsFL)
{
    const int t = threadIdx.x;
    if (t < 128) {
        float s = 0.f;
#pragma unroll
        for (int bin = 0; bin < SBINS; ++bin) s += statsPL[bin * 128 + t];
        statsFL[t] = s;
    }
}

// =====================================================================
// build point-major input records: xall[b][p][0..2]=coords, [3..66]=feats,
// [67]=pad (272 B record, float4-aligned)
// =====================================================================
__global__ __launch_bounds__(256) void build_xall(const float* __restrict__ coords,
                                                  const float* __restrict__ feats,
                                                  float* __restrict__ xall)
{
    const int tid = blockIdx.x * 256 + threadIdx.x;   // b*NPTS + p
    const int b = tid >> 13, p = tid & (NPTS - 1);
    const float* cb = coords + (size_t)b * 3 * NPTS;
    const float* fb = feats + (size_t)b * CFEAT * NPTS;
    float* xp = xall + (size_t)tid * 68;
    xp[0] = cb[p]; xp[1] = cb[NPTS + p]; xp[2] = cb[2 * NPTS + p];
#pragma unroll
    for (int c = 0; c < CFEAT; ++c) xp[3 + c] = fb[c * NPTS + p];
    xp[67] = 0.f;
}

// =====================================================================
// FPS: 1 block/batch, 512 threads, 16 pts/thread in VGPRs; coords in
// LDS for broadcast reads; one barrier/iter via double-buffered packs.
// No-contract fp32 matches numpy ((dx*dx+dy*dy)+dz*dz) bitwise.
// =====================================================================
__global__ __launch_bounds__(512) void fps_kernel(const float* __restrict__ coords,
                                                  int* __restrict__ cidx)
{
    extern __shared__ float smem[];
    float* sx = smem;
    float* sy = smem + NPTS;
    float* sz = smem + 2 * NPTS;
    unsigned long long* wpack = (unsigned long long*)(smem + 3 * NPTS);  // [2][8]

    const int b = blockIdx.x;
    const int t = threadIdx.x;
    const float* cb = coords + (size_t)b * 3 * NPTS;

    float X[16], Y[16], Z[16], mind[16];
#pragma unroll
    for (int j = 0; j < 16; ++j) {
        int p = t + j * 512;
        X[j] = cb[p];
        Y[j] = cb[NPTS + p];
        Z[j] = cb[2 * NPTS + p];
        sx[p] = X[j]; sy[p] = Y[j]; sz[p] = Z[j];
        mind[j] = 1e10f;
    }
    if (t == 0) cidx[b * NC] = 0;
    __syncthreads();

    int cur = 0;
    for (int it = 1; it < NC; ++it) {
        const float lx = sx[cur], ly = sy[cur], lz = sz[cur];
        float bv = -1.0f; int bi = 0;
#pragma unroll
        for (int j = 0; j < 16; ++j) {
            float dx = __fsub_rn(X[j], lx);
            float dy = __fsub_rn(Y[j], ly);
            float dz = __fsub_rn(Z[j], lz);
            float d  = __fadd_rn(__fadd_rn(__fmul_rn(dx, dx), __fmul_rn(dy, dy)),
                                 __fmul_rn(dz, dz));
            float nm = fminf(mind[j], d);
            mind[j] = nm;
            if (nm > bv) { bv = nm; bi = t + j * 512; }   // strict >: lowest idx
        }
        unsigned long long pack = ((unsigned long long)__float_as_uint(bv) << 32)
                                | (unsigned long long)(unsigned)(NPTS - 1 - bi);
#pragma unroll
        for (int o = 32; o > 0; o >>= 1) {
            unsigned long long other = __shfl_xor(pack, o);
            if (other > pack) pack = other;
        }
        unsigned long long* wp = wpack + (it & 1) * 8;
        if ((t & 63) == 0) wp[t >> 6] = pack;
        __syncthreads();
        unsigned long long best = wp[0];
#pragma unroll
        for (int w = 1; w < 8; ++w) {
            unsigned long long v = wp[w];
            if (v > best) best = v;
        }
        cur = NPTS - 1 - (int)(best & 0xffffffffu);
        if (t == 0) cidx[b * NC + it] = cur;
    }
}

// =====================================================================
// Ball query -> nidx + centers. EXPANDED d2 form (cn+pn)-2*cp, no fma.
// =====================================================================
__global__ __launch_bounds__(256) void bq_kernel(const float* __restrict__ coords,
                                                 const int* __restrict__ cidx,
                                                 int* __restrict__ nidx,
                                                 float* __restrict__ centers)
{
    const int s = blockIdx.x, b = blockIdx.y, t = threadIdx.x;
    __shared__ int s_idx[KNN];
    __shared__ int s_pref[9];
    __shared__ float s_c[3];
    __shared__ float s_cn;
    const float* cb = coords + (size_t)b * 3 * NPTS;
    if (t == 0) {
        int ci = cidx[b * NC + s];
        float cx = cb[ci], cy = cb[NPTS + ci], cz = cb[2 * NPTS + ci];
        s_c[0] = cx; s_c[1] = cy; s_c[2] = cz;
        s_cn = __fadd_rn(__fadd_rn(__fmul_rn(cx, cx), __fmul_rn(cy, cy)),
                         __fmul_rn(cz, cz));
    }
    __syncthreads();
    const float cx = s_c[0], cy = s_c[1], cz = s_c[2], cn = s_cn;
    const int base = t * 32;
    int cnt = 0;
    for (int j = 0; j < 32; ++j) {
        int p = base + j;
        float x = cb[p], y = cb[NPTS + p], z = cb[2 * NPTS + p];
        float pn = __fadd_rn(__fadd_rn(__fmul_rn(x, x), __fmul_rn(y, y)), __fmul_rn(z, z));
        float cp = __fadd_rn(__fadd_rn(__fmul_rn(cx, x), __fmul_rn(cy, y)), __fmul_rn(cz, z));
        float d2 = __fsub_rn(__fadd_rn(cn, pn), __fmul_rn(2.0f, cp));
        if (d2 < R2) ++cnt;
    }
    const int lane = t & 63, wid = t >> 6;
    int incl = cnt;
    for (int o = 1; o < 64; o <<= 1) {
        int v = __shfl_up(incl, o);
        if (lane >= o) incl += v;
    }
    if (lane == 63) s_pref[wid] = incl;
    __syncthreads();
    int ex = incl - cnt;
    for (int w = 0; w < wid; ++w) ex += s_pref[w];
    if (t == 255) s_pref[8] = ex + cnt;
    if (ex < KNN && cnt > 0) {
        int slot = ex;
        for (int j = 0; j < 32 && slot < KNN; ++j) {
            int p = base + j;
            float x = cb[p], y = cb[NPTS + p], z = cb[2 * NPTS + p];
            float pn = __fadd_rn(__fadd_rn(__fmul_rn(x, x), __fmul_rn(y, y)), __fmul_rn(z, z));
            float cp = __fadd_rn(__fadd_rn(__fmul_rn(cx, x), __fmul_rn(cy, y)), __fmul_rn(cz, z));
            float d2 = __fsub_rn(__fadd_rn(cn, pn), __fmul_rn(2.0f, cp));
            if (d2 < R2) { s_idx[slot] = p; ++slot; }
        }
    }
    __syncthreads();
    const int total = s_pref[8];
    if (t < KNN) {
        int v = (total == 0) ? 0 : ((t < total) ? s_idx[t] : s_idx[0]);
        nidx[(b * NC + s) * KNN + t] = v;
    }
    if (t < 3) centers[(b * NC + s) * 3 + t] = s_c[t];
}

// =====================================================================
// Layer 1: block = 64 cols x 4 out-chunks of 16. Gather staged in LDS
// xs[68][64] fp32; per-thread state is only acc[16] (no spill).
// =====================================================================
__global__ __launch_bounds__(256) void l1_kernel(const float* __restrict__ xall,
                                                 const int* __restrict__ nidx,
                                                 const float* __restrict__ centers,
                                                 const float* __restrict__ wt,
                                                 const float* __restrict__ b0,
                                                 float* __restrict__ Y,
                                                 float* __restrict__ statsPL)
{
    __shared__ float sw[67 * 64 + 64];
    __shared__ float xs[68 * 64];
    __shared__ float s_sum[8], s_sq[8];
    const int b = blockIdx.y, t = threadIdx.x;
    const int col = t & 63, q = t >> 6;
    const int n = blockIdx.x * 64 + col;
    for (int i = t; i < 67 * 64; i += 256) sw[i] = wt[i];
    if (t < 64) sw[67 * 64 + t] = b0[t];
    if (t < 8) { s_sum[t] = 0.f; s_sq[t] = 0.f; }
    // gather this column's point; q covers float4s [4q,4q+4), q==3 also #16
    const int s = n >> 5, k = n & 31;
    const int p = nidx[(b * NC + s) * KNN + k];
    const float4* xp4 = (const float4*)(xall + (size_t)(b * NPTS + p) * 68);
    const float* cc = centers + (size_t)(b * NC + s) * 3;
#pragma unroll
    for (int r = 0; r < 4; ++r) {
        float4 v = xp4[q * 4 + r];
        int ch = (q * 4 + r) * 4;
        if (ch == 0) { v.x -= cc[0]; v.y -= cc[1]; v.z -= cc[2]; }
        xs[(ch + 0) * 64 + col] = v.x;
        xs[(ch + 1) * 64 + col] = v.y;
        xs[(ch + 2) * 64 + col] = v.z;
        xs[(ch + 3) * 64 + col] = v.w;
    }
    if (q == 3) {
        float4 v = xp4[16];
        xs[64 * 64 + col] = v.x;
        xs[65 * 64 + col] = v.y;
        xs[66 * 64 + col] = v.z;
        xs[67 * 64 + col] = v.w;
    }
    __syncthreads();
    // compute out channels [q*16, q*16+16)
    float acc[16];
#pragma unroll
    for (int o = 0; o < 16; ++o) acc[o] = sw[67 * 64 + q * 16 + o];
    for (int i = 0; i < 67; ++i) {
        float xv = xs[i * 64 + col];
        const float* wr = sw + i * 64 + q * 16;
#pragma unroll
        for (int o = 0; o < 16; ++o) acc[o] = fmaf(wr[o], xv, acc[o]);
    }
    float* yb = Y + (size_t)b * 64 * NSCOL + n;
#pragma unroll
    for (int o = 0; o < 16; ++o) yb[(size_t)(q * 16 + o) * NSCOL] = acc[o];
#pragma unroll
    for (int g = 0; g < 2; ++g) {                 // GN groups q*2+g (8 ch)
        float sv = 0.f, sq = 0.f;
#pragma unroll
        for (int j = 0; j < 8; ++j) { float vv = acc[g * 8 + j]; sv += vv; sq = fmaf(vv, vv, sq); }
#pragma unroll
        for (int o = 32; o > 0; o >>= 1) { sv += __shfl_xor(sv, o); sq += __shfl_xor(sq, o); }
        if ((t & 63) == 0) { atomicAdd(&s_sum[q * 2 + g], sv); atomicAdd(&s_sq[q * 2 + g], sq); }
    }
    __syncthreads();
    if (t < 16) {
        const int bin = blockIdx.x & (SBINS - 1);
        const int g = t >> 1, kk = t & 1;
        atomicAdd(&statsPL[bin * 128 + (b * 8 + g) * 2 + kk], kk ? s_sq[g] : s_sum[g]);
    }
}

// =====================================================================
// Layer 2: in-place, block = 64 cols x 4 out-chunks of 16.
// GN1+SiLU staged to LDS xs[64][64] fp32.
// =====================================================================
__global__ __launch_bounds__(256) void l2_kernel(const float* __restrict__ wt1,
                                                 const float* __restrict__ b1,
                                                 const float* __restrict__ g0,
                                                 const float* __restrict__ be0,
                                                 const float* __restrict__ statsF_in,
                                                 float* __restrict__ statsPL,
                                                 float* __restrict__ Y)
{
    __shared__ float sw[64 * 64 + 64];
    __shared__ float xs[64 * 64];
    __shared__ float sA[64], sB[64];
    __shared__ float s_sum[8], s_sq[8];
    const int b = blockIdx.y, t = threadIdx.x;
    const int col = t & 63, q = t >> 6;
    const int n = blockIdx.x * 64 + col;
    for (int i = t; i < 64 * 64; i += 256) sw[i] = wt1[i];
    if (t < 64) {
        sw[64 * 64 + t] = b1[t];
        const int g = t >> 3;
        const float inv = 1.0f / (8.0f * NSCOL);
        float mu = statsF_in[(b * 8 + g) * 2 + 0] * inv;
        float var = statsF_in[(b * 8 + g) * 2 + 1] * inv - mu * mu;
        float A = (1.0f / sqrtf(var + GN_EPS)) * g0[t];
        sA[t] = A; sB[t] = be0[t] - mu * A;
    }
    if (t < 8) { s_sum[t] = 0.f; s_sq[t] = 0.f; }
    __syncthreads();
    float* yb = Y + (size_t)b * 64 * NSCOL + n;
#pragma unroll
    for (int r = 0; r < 16; ++r) {                // stage rows [q*16, q*16+16)
        int i = q * 16 + r;
        float raw = yb[(size_t)i * NSCOL];
        float v = fmaf(raw, sA[i], sB[i]);
        xs[i * 64 + col] = v * __builtin_amdgcn_rcpf(1.0f + __expf(-v));
    }
    __syncthreads();
    float acc[16];
#pragma unroll
    for (int o = 0; o < 16; ++o) acc[o] = sw[64 * 64 + q * 16 + o];
    for (int i = 0; i < 64; ++i) {
        float xv = xs[i * 64 + col];
        const float* wr = sw + i * 64 + q * 16;
#pragma unroll
        for (int o = 0; o < 16; ++o) acc[o] = fmaf(wr[o], xv, acc[o]);
    }
#pragma unroll
    for (int o = 0; o < 16; ++o) yb[(size_t)(q * 16 + o) * NSCOL] = acc[o];
#pragma unroll
    for (int g = 0; g < 2; ++g) {
        float sv = 0.f, sq = 0.f;
#pragma unroll
        for (int j = 0; j < 8; ++j) { float vv = acc[g * 8 + j]; sv += vv; sq = fmaf(vv, vv, sq); }
#pragma unroll
        for (int o = 32; o > 0; o >>= 1) { sv += __shfl_xor(sv, o); sq += __shfl_xor(sq, o); }
        if ((t & 63) == 0) { atomicAdd(&s_sum[q * 2 + g], sv); atomicAdd(&s_sq[q * 2 + g], sq); }
    }
    __syncthreads();
    if (t < 16) {
        const int bin = blockIdx.x & (SBINS - 1);
        const int g = t >> 1, kk = t & 1;
        atomicAdd(&statsPL[bin * 128 + (b * 8 + g) * 2 + kk], kk ? s_sq[g] : s_sum[g]);
    }
}

// =====================================================================
// Layer 3: in-place, block = 64 cols x 4 out-chunks of 32 (128 out).
// GN2+SiLU staged to LDS xs[64][64] fp32; stats on fp32 acc; output
// bf16 pair-packed into the same 256B/col footprint.
// =====================================================================
__global__ __launch_bounds__(256) void l3_kernel(const float* __restrict__ wt2,
                                                 const float* __restrict__ b2,
                                                 const float* __restrict__ g1,
                                                 const float* __restrict__ be1,
                                                 const float* __restrict__ statsF_in,
                                                 float* __restrict__ statsPL,
                                                 float* __restrict__ Y)
{
    __shared__ float sw[64 * 128 + 128];
    __shared__ float xs[64 * 64];
    __shared__ float sA[64], sB[64];
    __shared__ float s_sum[8], s_sq[8];
    const int b = blockIdx.y, t = threadIdx.x;
    const int col = t & 63, q = t >> 6;
    const int n = blockIdx.x * 64 + col;
    for (int i = t; i < 64 * 128; i += 256) sw[i] = wt2[i];
    if (t < 128) sw[64 * 128 + t] = b2[t];
    if (t < 64) {
        const int g = t >> 3;
        const float inv = 1.0f / (8.0f * NSCOL);
        float mu = statsF_in[(b * 8 + g) * 2 + 0] * inv;
        float var = statsF_in[(b * 8 + g) * 2 + 1] * inv - mu * mu;
        float A = (1.0f / sqrtf(var + GN_EPS)) * g1[t];
        sA[t] = A; sB[t] = be1[t] - mu * A;
    }
    if (t < 8) { s_sum[t] = 0.f; s_sq[t] = 0.f; }
    __syncthreads();
    float* yb = Y + (size_t)b * 64 * NSCOL + n;
#pragma unroll
    for (int r = 0; r < 16; ++r) {
        int i = q * 16 + r;
        float raw = yb[(size_t)i * NSCOL];
        float v = fmaf(raw, sA[i], sB[i]);
        xs[i * 64 + col] = v * __builtin_amdgcn_rcpf(1.0f + __expf(-v));
    }
    __syncthreads();
    float acc[32];                                 // out channels [q*32, q*32+32)
#pragma unroll
    for (int o = 0; o < 32; ++o) acc[o] = sw[64 * 128 + q * 32 + o];
    for (int i = 0; i < 64; ++i) {
        float xv = xs[i * 64 + col];
        const float* wr = sw + i * 128 + q * 32;
#pragma unroll
        for (int o = 0; o < 32; ++o) acc[o] = fmaf(wr[o], xv, acc[o]);
    }
#pragma unroll
    for (int g = 0; g < 2; ++g) {                  // GN groups q*2+g (16 ch)
        float sv = 0.f, sq = 0.f;
#pragma unroll
        for (int j = 0; j < 16; ++j) { float vv = acc[g * 16 + j]; sv += vv; sq = fmaf(vv, vv, sq); }
#pragma unroll
        for (int o = 32; o > 0; o >>= 1) { sv += __shfl_xor(sv, o); sq += __shfl_xor(sq, o); }
        if ((t & 63) == 0) { atomicAdd(&s_sum[q * 2 + g], sv); atomicAdd(&s_sq[q * 2 + g], sq); }
    }
    unsigned* yu = (unsigned*)yb;
#pragma unroll
    for (int j = 0; j < 16; ++j) {                 // pack uint rows [q*16, q*16+16)
        unsigned u = f2bf(acc[2 * j]) | (f2bf(acc[2 * j + 1]) << 16);
        yu[(size_t)(q * 16 + j) * NSCOL] = u;
    }
    __syncthreads();
    if (t < 16) {
        const int bin = blockIdx.x & (SBINS - 1);
        const int g = t >> 1, kk = t & 1;
        atomicAdd(&statsPL[bin * 128 + (b * 8 + g) * 2 + kk], kk ? s_sq[g] : s_sum[g]);
    }
}

// =====================================================================
// Finalize: GN3 + SiLU + max over K. Thread per (b, channel-PAIR, s).
// =====================================================================
__global__ __launch_bounds__(256) void fin_kernel(const unsigned* __restrict__ Yu,
                                                  const float* __restrict__ g2,
                                                  const float* __restrict__ be2,
                                                  const float* __restrict__ stats,
                                                  float* __restrict__ out)
{
    const int tid = blockIdx.x * 256 + threadIdx.x;
    const int s = tid & (NC - 1);
    const int cp = (tid >> 11) & 63;
    const int b = tid >> 17;
    const int g = cp >> 3;
    const float inv = 1.0f / (16.0f * NSCOL);
    float mu = stats[(b * 8 + g) * 2 + 0] * inv;
    float var = stats[(b * 8 + g) * 2 + 1] * inv - mu * mu;
    float rs = 1.0f / sqrtf(var + GN_EPS);
    const int c0 = cp * 2, c1 = c0 + 1;
    float A0 = rs * g2[c0], B0 = be2[c0] - mu * A0;
    float A1 = rs * g2[c1], B1 = be2[c1] - mu * A1;
    const unsigned* yb = Yu + (size_t)(b * 64 + cp) * NSCOL + s * KNN;
    float m0 = -INFINITY, m1 = -INFINITY;
#pragma unroll
    for (int qq = 0; qq < 8; ++qq) {
        uint4 v = ((const uint4*)yb)[qq];
        unsigned uu[4] = {v.x, v.y, v.z, v.w};
#pragma unroll
        for (int r = 0; r < 4; ++r) {
            float f0 = __uint_as_float(uu[r] << 16);
            float f1 = __uint_as_float(uu[r] & 0xffff0000u);
            float v0 = fmaf(f0, A0, B0);
            v0 = v0 * __builtin_amdgcn_rcpf(1.0f + __expf(-v0));
            m0 = fmaxf(m0, v0);
            float v1 = fmaf(f1, A1, B1);
            v1 = v1 * __builtin_amdgcn_rcpf(1.0f + __expf(-v1));
            m1 = fmaxf(m1, v1);
        }
    }
    out[(size_t)(b * 128 + c0) * NC + s] = m0;
    out[(size_t)(b * 128 + c1) * NC + s] = m1;
}

// =====================================================================
extern "C" void kernel_launch(void* const* d_in, const int* in_sizes, int n_in,
                              void* d_out, int out_size, void* d_ws, size_t ws_size,
                              hipStream_t stream)
{
    if (ws_size < WS_NEEDED) return;

    const float* coords = (const float*)d_in[0];
    const float* feats  = (const float*)d_in[1];
    const float* w0  = (const float*)d_in[2];
    const float* b0  = (const float*)d_in[3];
    const float* g0  = (const float*)d_in[4];
    const float* be0 = (const float*)d_in[5];
    const float* w1  = (const float*)d_in[6];
    const float* b1  = (const float*)d_in[7];
    const float* g1  = (const float*)d_in[8];
    const float* be1 = (const float*)d_in[9];
    const float* w2  = (const float*)d_in[10];
    const float* b2  = (const float*)d_in[11];
    const float* g2  = (const float*)d_in[12];
    const float* be2 = (const float*)d_in[13];
    float* out = (float*)d_out;

    char* ws = (char*)d_ws;
    int*   cidx    = (int*)(ws + OFF_CIDX);
    int*   nidx    = (int*)(ws + OFF_NIDX);
    float* centers = (float*)(ws + OFF_CENT);
    float* statsP  = (float*)(ws + OFF_STATSP);   // [3][SBINS][128]
    float* statsF  = (float*)(ws + OFF_STATSF);   // [3][128]
    float* wt      = (float*)(ws + OFF_WT);
    float* xall    = (float*)(ws + OFF_XALL);
    float* Ybuf    = (float*)(ws + OFF_Y);

    prep_kernel<<<48, 256, 0, stream>>>(w0, w1, w2, statsP, statsF, wt);
    build_xall<<<(BATCH * NPTS) / 256, 256, 0, stream>>>(coords, feats, xall);
    fps_kernel<<<BATCH, 512, 3 * NPTS * 4 + 128, stream>>>(coords, cidx);
    bq_kernel<<<dim3(NC, BATCH), 256, 0, stream>>>(coords, cidx, nidx, centers);

    const dim3 lgrid(NSCOL / 64, BATCH);
    l1_kernel<<<lgrid, 256, 0, stream>>>(xall, nidx, centers, wt, b0, Ybuf, statsP);
    reduce_stats<<<1, 128, 0, stream>>>(statsP, statsF);
    l2_kernel<<<lgrid, 256, 0, stream>>>(wt + 4288, b1, g0, be0,
                                         statsF, statsP + SBINS * 128, Ybuf);
    reduce_stats<<<1, 128, 0, stream>>>(statsP + SBINS * 128, statsF + 128);
    l3_kernel<<<lgrid, 256, 0, stream>>>(wt + 8384, b2, g1, be1,
                                         statsF + 128, statsP + 2 * SBINS * 128, Ybuf);
    reduce_stats<<<1, 128, 0, stream>>>(statsP + 2 * SBINS * 128, statsF + 256);
    fin_kernel<<<(BATCH * 64 * NC) / 256, 256, 0, stream>>>(
        (const unsigned*)Ybuf, g2, be2, statsF + 256, out);
    (void)in_sizes; (void)n_in; (void)out_size;
}

// Round 7
// 2946.850 us; speedup vs baseline: 2.2491x; 1.0493x over previous
//
#include <hip/hip_runtime.h>
#include <math.h>

#define BATCH 8
#define NPTS 8192
#define CFEAT 64
#define NC 2048           // S centers
#define KNN 32
#define NSCOL (NC*KNN)    // 65536 columns per batch
#define R2 0.0625f        // radius^2
#define GN_EPS 1e-5f
#define SBINS 32          // stat partial bins (cuts atomic contention 32x)

// ---- workspace layout (bytes) ----
#define OFF_CIDX   0ull
#define OFF_NIDX   65536ull
#define OFF_CENT   2162688ull
#define OFF_STATSP 2359296ull            // 3 layers x 32 bins x 128 fl = 49152 B
#define OFF_STATSF 2408448ull            // 3 x 128 fl = 1536 B
#define OFF_WT     2410496ull            // 16576 fl = 66304 B
#define OFF_XALL   4194304ull            // 17,825,792 B
#define OFF_Y      23068672ull           // 134,217,728 B
#define WS_NEEDED  (OFF_Y + 8ull*64*NSCOL*4ull)   // 150 MiB

static __device__ __forceinline__ unsigned f2bf(float f) {
    unsigned u = __float_as_uint(f);
    return (u + 0x7fffu + ((u >> 16) & 1u)) >> 16;   // RNE, finite inputs
}

// =====================================================================
// prep: zero stat partials/finals; transpose weights to [i][o] layout.
// =====================================================================
__global__ void prep_kernel(const float* __restrict__ w0, const float* __restrict__ w1,
                            const float* __restrict__ w2, float* __restrict__ statsP,
                            float* __restrict__ statsF, float* __restrict__ wt)
{
    const int t = blockIdx.x * 256 + threadIdx.x;
    if (t < 3 * SBINS * 128) statsP[t] = 0.f;
    if (t < 384) statsF[t] = 0.f;
    if (t < 64 * 67) { int o = t / 67, i = t - o * 67; wt[i * 64 + o] = w0[t]; }
    if (t < 64 * 64) { int o = t >> 6, i = t & 63;     wt[4288 + i * 64 + o] = w1[t]; }
    if (t < 128 * 64){ int o = t >> 6, i = t & 63;     wt[8384 + i * 128 + o] = w2[t]; }
}

// =====================================================================
__global__ void reduce_stats(const float* __restrict__ statsPL, float* __restrict__ statsFL)
{
    const int t = threadIdx.x;
    if (t < 128) {
        float s = 0.f;
#pragma unroll
        for (int bin = 0; bin < SBINS; ++bin) s += statsPL[bin * 128 + t];
        statsFL[t] = s;
    }
}

// =====================================================================
// build point-major input records: xall[b][p][0..2]=coords, [3..66]=feats,
// [67]=pad (272 B record, float4-aligned)
// =====================================================================
__global__ __launch_bounds__(256) void build_xall(const float* __restrict__ coords,
                                                  const float* __restrict__ feats,
                                                  float* __restrict__ xall)
{
    const int tid = blockIdx.x * 256 + threadIdx.x;   // b*NPTS + p
    const int b = tid >> 13, p = tid & (NPTS - 1);
    const float* cb = coords + (size_t)b * 3 * NPTS;
    const float* fb = feats + (size_t)b * CFEAT * NPTS;
    float* xp = xall + (size_t)tid * 68;
    xp[0] = cb[p]; xp[1] = cb[NPTS + p]; xp[2] = cb[2 * NPTS + p];
#pragma unroll
    for (int c = 0; c < CFEAT; ++c) xp[3 + c] = fb[c * NPTS + p];
    xp[67] = 0.f;
}

// =====================================================================
// FPS v3: 1 block/batch, 256 threads, 32 pts/thread PINNED in VGPRs
// (asm barrier defeats the compiler's LDS-CSE that made R6 re-read
// coords from LDS every iteration -- VGPR_Count was 60 < the 64 the
// arrays need). Coords also in LDS for the broadcast read of the
// current center. One barrier/iter, 4-slot double-buffered reduce.
// No-contract fp32 matches numpy ((dx*dx+dy*dy)+dz*dz) bitwise;
// u64-packed argmax keeps lowest index on ties (first occurrence).
// =====================================================================
__global__ __launch_bounds__(256) void fps_kernel(const float* __restrict__ coords,
                                                  int* __restrict__ cidx)
{
    extern __shared__ float smem[];
    float* sx = smem;
    float* sy = smem + NPTS;
    float* sz = smem + 2 * NPTS;
    unsigned long long* wpack = (unsigned long long*)(smem + 3 * NPTS);  // [2][4]

    const int b = blockIdx.x;
    const int t = threadIdx.x;
    const float* cb = coords + (size_t)b * 3 * NPTS;

    float X[32], Y[32], Z[32], mind[32];
#pragma unroll
    for (int j = 0; j < 32; ++j) {
        int p = t + j * 256;
        X[j] = cb[p];
        Y[j] = cb[NPTS + p];
        Z[j] = cb[2 * NPTS + p];
        sx[p] = X[j]; sy[p] = Y[j]; sz[p] = Z[j];
        mind[j] = 1e10f;
        // pin private copies in VGPRs: compiler may no longer fold them
        // into ds_reads of sx/sy/sz
        asm volatile("" : "+v"(X[j]), "+v"(Y[j]), "+v"(Z[j]));
    }
    if (t == 0) cidx[b * NC] = 0;
    __syncthreads();

    int cur = 0;
    for (int it = 1; it < NC; ++it) {
        const float lx = sx[cur], ly = sy[cur], lz = sz[cur];  // broadcast
        float bv = -1.0f; int bi = 0;
#pragma unroll
        for (int j = 0; j < 32; ++j) {
            float dx = __fsub_rn(X[j], lx);
            float dy = __fsub_rn(Y[j], ly);
            float dz = __fsub_rn(Z[j], lz);
            float d  = __fadd_rn(__fadd_rn(__fmul_rn(dx, dx), __fmul_rn(dy, dy)),
                                 __fmul_rn(dz, dz));
            float nm = fminf(mind[j], d);
            mind[j] = nm;
            if (nm > bv) { bv = nm; bi = t + j * 256; }   // strict >: lowest idx
        }
        unsigned long long pack = ((unsigned long long)__float_as_uint(bv) << 32)
                                | (unsigned long long)(unsigned)(NPTS - 1 - bi);
#pragma unroll
        for (int o = 32; o > 0; o >>= 1) {
            unsigned long long other = __shfl_xor(pack, o);
            if (other > pack) pack = other;
        }
        unsigned long long* wp = wpack + (it & 1) * 4;     // double buffer
        if ((t & 63) == 0) wp[t >> 6] = pack;
        __syncthreads();
        unsigned long long best = wp[0];
#pragma unroll
        for (int w = 1; w < 4; ++w) {
            unsigned long long v = wp[w];
            if (v > best) best = v;
        }
        cur = NPTS - 1 - (int)(best & 0xffffffffu);
        if (t == 0) cidx[b * NC + it] = cur;
    }
}

// =====================================================================
// Ball query -> nidx + centers. EXPANDED d2 form (cn+pn)-2*cp, no fma.
// =====================================================================
__global__ __launch_bounds__(256) void bq_kernel(const float* __restrict__ coords,
                                                 const int* __restrict__ cidx,
                                                 int* __restrict__ nidx,
                                                 float* __restrict__ centers)
{
    const int s = blockIdx.x, b = blockIdx.y, t = threadIdx.x;
    __shared__ int s_idx[KNN];
    __shared__ int s_pref[9];
    __shared__ float s_c[3];
    __shared__ float s_cn;
    const float* cb = coords + (size_t)b * 3 * NPTS;
    if (t == 0) {
        int ci = cidx[b * NC + s];
        float cx = cb[ci], cy = cb[NPTS + ci], cz = cb[2 * NPTS + ci];
        s_c[0] = cx; s_c[1] = cy; s_c[2] = cz;
        s_cn = __fadd_rn(__fadd_rn(__fmul_rn(cx, cx), __fmul_rn(cy, cy)),
                         __fmul_rn(cz, cz));
    }
    __syncthreads();
    const float cx = s_c[0], cy = s_c[1], cz = s_c[2], cn = s_cn;
    const int base = t * 32;
    int cnt = 0;
    for (int j = 0; j < 32; ++j) {
        int p = base + j;
        float x = cb[p], y = cb[NPTS + p], z = cb[2 * NPTS + p];
        float pn = __fadd_rn(__fadd_rn(__fmul_rn(x, x), __fmul_rn(y, y)), __fmul_rn(z, z));
        float cp = __fadd_rn(__fadd_rn(__fmul_rn(cx, x), __fmul_rn(cy, y)), __fmul_rn(cz, z));
        float d2 = __fsub_rn(__fadd_rn(cn, pn), __fmul_rn(2.0f, cp));
        if (d2 < R2) ++cnt;
    }
    const int lane = t & 63, wid = t >> 6;
    int incl = cnt;
    for (int o = 1; o < 64; o <<= 1) {
        int v = __shfl_up(incl, o);
        if (lane >= o) incl += v;
    }
    if (lane == 63) s_pref[wid] = incl;
    __syncthreads();
    int ex = incl - cnt;
    for (int w = 0; w < wid; ++w) ex += s_pref[w];
    if (t == 255) s_pref[8] = ex + cnt;
    if (ex < KNN && cnt > 0) {
        int slot = ex;
        for (int j = 0; j < 32 && slot < KNN; ++j) {
            int p = base + j;
            float x = cb[p], y = cb[NPTS + p], z = cb[2 * NPTS + p];
            float pn = __fadd_rn(__fadd_rn(__fmul_rn(x, x), __fmul_rn(y, y)), __fmul_rn(z, z));
            float cp = __fadd_rn(__fadd_rn(__fmul_rn(cx, x), __fmul_rn(cy, y)), __fmul_rn(cz, z));
            float d2 = __fsub_rn(__fadd_rn(cn, pn), __fmul_rn(2.0f, cp));
            if (d2 < R2) { s_idx[slot] = p; ++slot; }
        }
    }
    __syncthreads();
    const int total = s_pref[8];
    if (t < KNN) {
        int v = (total == 0) ? 0 : ((t < total) ? s_idx[t] : s_idx[0]);
        nidx[(b * NC + s) * KNN + t] = v;
    }
    if (t < 3) centers[(b * NC + s) * 3 + t] = s_c[t];
}

// =====================================================================
// Layer 1: block = 64 cols x 4 out-chunks of 16. Gather staged in LDS
// xs[68][64] fp32; per-thread state is only acc[16] (no spill).
// =====================================================================
__global__ __launch_bounds__(256) void l1_kernel(const float* __restrict__ xall,
                                                 const int* __restrict__ nidx,
                                                 const float* __restrict__ centers,
                                                 const float* __restrict__ wt,
                                                 const float* __restrict__ b0,
                                                 float* __restrict__ Y,
                                                 float* __restrict__ statsPL)
{
    __shared__ float sw[67 * 64 + 64];
    __shared__ float xs[68 * 64];
    __shared__ float s_sum[8], s_sq[8];
    const int b = blockIdx.y, t = threadIdx.x;
    const int col = t & 63, q = t >> 6;
    const int n = blockIdx.x * 64 + col;
    for (int i = t; i < 67 * 64; i += 256) sw[i] = wt[i];
    if (t < 64) sw[67 * 64 + t] = b0[t];
    if (t < 8) { s_sum[t] = 0.f; s_sq[t] = 0.f; }
    const int s = n >> 5, k = n & 31;
    const int p = nidx[(b * NC + s) * KNN + k];
    const float4* xp4 = (const float4*)(xall + (size_t)(b * NPTS + p) * 68);
    const float* cc = centers + (size_t)(b * NC + s) * 3;
#pragma unroll
    for (int r = 0; r < 4; ++r) {
        float4 v = xp4[q * 4 + r];
        int ch = (q * 4 + r) * 4;
        if (ch == 0) { v.x -= cc[0]; v.y -= cc[1]; v.z -= cc[2]; }
        xs[(ch + 0) * 64 + col] = v.x;
        xs[(ch + 1) * 64 + col] = v.y;
        xs[(ch + 2) * 64 + col] = v.z;
        xs[(ch + 3) * 64 + col] = v.w;
    }
    if (q == 3) {
        float4 v = xp4[16];
        xs[64 * 64 + col] = v.x;
        xs[65 * 64 + col] = v.y;
        xs[66 * 64 + col] = v.z;
        xs[67 * 64 + col] = v.w;
    }
    __syncthreads();
    float acc[16];
#pragma unroll
    for (int o = 0; o < 16; ++o) acc[o] = sw[67 * 64 + q * 16 + o];
    for (int i = 0; i < 67; ++i) {
        float xv = xs[i * 64 + col];
        const float* wr = sw + i * 64 + q * 16;
#pragma unroll
        for (int o = 0; o < 16; ++o) acc[o] = fmaf(wr[o], xv, acc[o]);
    }
    float* yb = Y + (size_t)b * 64 * NSCOL + n;
#pragma unroll
    for (int o = 0; o < 16; ++o) yb[(size_t)(q * 16 + o) * NSCOL] = acc[o];
#pragma unroll
    for (int g = 0; g < 2; ++g) {
        float sv = 0.f, sq = 0.f;
#pragma unroll
        for (int j = 0; j < 8; ++j) { float vv = acc[g * 8 + j]; sv += vv; sq = fmaf(vv, vv, sq); }
#pragma unroll
        for (int o = 32; o > 0; o >>= 1) { sv += __shfl_xor(sv, o); sq += __shfl_xor(sq, o); }
        if ((t & 63) == 0) { atomicAdd(&s_sum[q * 2 + g], sv); atomicAdd(&s_sq[q * 2 + g], sq); }
    }
    __syncthreads();
    if (t < 16) {
        const int bin = blockIdx.x & (SBINS - 1);
        const int g = t >> 1, kk = t & 1;
        atomicAdd(&statsPL[bin * 128 + (b * 8 + g) * 2 + kk], kk ? s_sq[g] : s_sum[g]);
    }
}

// =====================================================================
// Layer 2: in-place, block = 64 cols x 4 out-chunks of 16.
// =====================================================================
__global__ __launch_bounds__(256) void l2_kernel(const float* __restrict__ wt1,
                                                 const float* __restrict__ b1,
                                                 const float* __restrict__ g0,
                                                 const float* __restrict__ be0,
                                                 const float* __restrict__ statsF_in,
                                                 float* __restrict__ statsPL,
                                                 float* __restrict__ Y)
{
    __shared__ float sw[64 * 64 + 64];
    __shared__ float xs[64 * 64];
    __shared__ float sA[64], sB[64];
    __shared__ float s_sum[8], s_sq[8];
    const int b = blockIdx.y, t = threadIdx.x;
    const int col = t & 63, q = t >> 6;
    const int n = blockIdx.x * 64 + col;
    for (int i = t; i < 64 * 64; i += 256) sw[i] = wt1[i];
    if (t < 64) {
        sw[64 * 64 + t] = b1[t];
        const int g = t >> 3;
        const float inv = 1.0f / (8.0f * NSCOL);
        float mu = statsF_in[(b * 8 + g) * 2 + 0] * inv;
        float var = statsF_in[(b * 8 + g) * 2 + 1] * inv - mu * mu;
        float A = (1.0f / sqrtf(var + GN_EPS)) * g0[t];
        sA[t] = A; sB[t] = be0[t] - mu * A;
    }
    if (t < 8) { s_sum[t] = 0.f; s_sq[t] = 0.f; }
    __syncthreads();
    float* yb = Y + (size_t)b * 64 * NSCOL + n;
#pragma unroll
    for (int r = 0; r < 16; ++r) {
        int i = q * 16 + r;
        float raw = yb[(size_t)i * NSCOL];
        float v = fmaf(raw, sA[i], sB[i]);
        xs[i * 64 + col] = v * __builtin_amdgcn_rcpf(1.0f + __expf(-v));
    }
    __syncthreads();
    float acc[16];
#pragma unroll
    for (int o = 0; o < 16; ++o) acc[o] = sw[64 * 64 + q * 16 + o];
    for (int i = 0; i < 64; ++i) {
        float xv = xs[i * 64 + col];
        const float* wr = sw + i * 64 + q * 16;
#pragma unroll
        for (int o = 0; o < 16; ++o) acc[o] = fmaf(wr[o], xv, acc[o]);
    }
#pragma unroll
    for (int o = 0; o < 16; ++o) yb[(size_t)(q * 16 + o) * NSCOL] = acc[o];
#pragma unroll
    for (int g = 0; g < 2; ++g) {
        float sv = 0.f, sq = 0.f;
#pragma unroll
        for (int j = 0; j < 8; ++j) { float vv = acc[g * 8 + j]; sv += vv; sq = fmaf(vv, vv, sq); }
#pragma unroll
        for (int o = 32; o > 0; o >>= 1) { sv += __shfl_xor(sv, o); sq += __shfl_xor(sq, o); }
        if ((t & 63) == 0) { atomicAdd(&s_sum[q * 2 + g], sv); atomicAdd(&s_sq[q * 2 + g], sq); }
    }
    __syncthreads();
    if (t < 16) {
        const int bin = blockIdx.x & (SBINS - 1);
        const int g = t >> 1, kk = t & 1;
        atomicAdd(&statsPL[bin * 128 + (b * 8 + g) * 2 + kk], kk ? s_sq[g] : s_sum[g]);
    }
}

// =====================================================================
// Layer 3: in-place, block = 64 cols x 4 out-chunks of 32 (128 out).
// Output bf16 pair-packed into the same 256B/col footprint.
// =====================================================================
__global__ __launch_bounds__(256) void l3_kernel(const float* __restrict__ wt2,
                                                 const float* __restrict__ b2,
                                                 const float* __restrict__ g1,
                                                 const float* __restrict__ be1,
                                                 const float* __restrict__ statsF_in,
                                                 float* __restrict__ statsPL,
                                                 float* __restrict__ Y)
{
    __shared__ float sw[64 * 128 + 128];
    __shared__ float xs[64 * 64];
    __shared__ float sA[64], sB[64];
    __shared__ float s_sum[8], s_sq[8];
    const int b = blockIdx.y, t = threadIdx.x;
    const int col = t & 63, q = t >> 6;
    const int n = blockIdx.x * 64 + col;
    for (int i = t; i < 64 * 128; i += 256) sw[i] = wt2[i];
    if (t < 128) sw[64 * 128 + t] = b2[t];
    if (t < 64) {
        const int g = t >> 3;
        const float inv = 1.0f / (8.0f * NSCOL);
        float mu = statsF_in[(b * 8 + g) * 2 + 0] * inv;
        float var = statsF_in[(b * 8 + g) * 2 + 1] * inv - mu * mu;
        float A = (1.0f / sqrtf(var + GN_EPS)) * g1[t];
        sA[t] = A; sB[t] = be1[t] - mu * A;
    }
    if (t < 8) { s_sum[t] = 0.f; s_sq[t] = 0.f; }
    __syncthreads();
    float* yb = Y + (size_t)b * 64 * NSCOL + n;
#pragma unroll
    for (int r = 0; r < 16; ++r) {
        int i = q * 16 + r;
        float raw = yb[(size_t)i * NSCOL];
        float v = fmaf(raw, sA[i], sB[i]);
        xs[i * 64 + col] = v * __builtin_amdgcn_rcpf(1.0f + __expf(-v));
    }
    __syncthreads();
    float acc[32];
#pragma unroll
    for (int o = 0; o < 32; ++o) acc[o] = sw[64 * 128 + q * 32 + o];
    for (int i = 0; i < 64; ++i) {
        float xv = xs[i * 64 + col];
        const float* wr = sw + i * 128 + q * 32;
#pragma unroll
        for (int o = 0; o < 32; ++o) acc[o] = fmaf(wr[o], xv, acc[o]);
    }
#pragma unroll
    for (int g = 0; g < 2; ++g) {
        float sv = 0.f, sq = 0.f;
#pragma unroll
        for (int j = 0; j < 16; ++j) { float vv = acc[g * 16 + j]; sv += vv; sq = fmaf(vv, vv, sq); }
#pragma unroll
        for (int o = 32; o > 0; o >>= 1) { sv += __shfl_xor(sv, o); sq += __shfl_xor(sq, o); }
        if ((t & 63) == 0) { atomicAdd(&s_sum[q * 2 + g], sv); atomicAdd(&s_sq[q * 2 + g], sq); }
    }
    unsigned* yu = (unsigned*)yb;
#pragma unroll
    for (int j = 0; j < 16; ++j) {
        unsigned u = f2bf(acc[2 * j]) | (f2bf(acc[2 * j + 1]) << 16);
        yu[(size_t)(q * 16 + j) * NSCOL] = u;
    }
    __syncthreads();
    if (t < 16) {
        const int bin = blockIdx.x & (SBINS - 1);
        const int g = t >> 1, kk = t & 1;
        atomicAdd(&statsPL[bin * 128 + (b * 8 + g) * 2 + kk], kk ? s_sq[g] : s_sum[g]);
    }
}

// =====================================================================
// Finalize: GN3 + SiLU + max over K. Thread per (b, channel-PAIR, s).
// =====================================================================
__global__ __launch_bounds__(256) void fin_kernel(const unsigned* __restrict__ Yu,
                                                  const float* __restrict__ g2,
                                                  const float* __restrict__ be2,
                                                  const float* __restrict__ stats,
                                                  float* __restrict__ out)
{
    const int tid = blockIdx.x * 256 + threadIdx.x;
    const int s = tid & (NC - 1);
    const int cp = (tid >> 11) & 63;
    const int b = tid >> 17;
    const int g = cp >> 3;
    const float inv = 1.0f / (16.0f * NSCOL);
    float mu = stats[(b * 8 + g) * 2 + 0] * inv;
    float var = stats[(b * 8 + g) * 2 + 1] * inv - mu * mu;
    float rs = 1.0f / sqrtf(var + GN_EPS);
    const int c0 = cp * 2, c1 = c0 + 1;
    float A0 = rs * g2[c0], B0 = be2[c0] - mu * A0;
    float A1 = rs * g2[c1], B1 = be2[c1] - mu * A1;
    const unsigned* yb = Yu + (size_t)(b * 64 + cp) * NSCOL + s * KNN;
    float m0 = -INFINITY, m1 = -INFINITY;
#pragma unroll
    for (int qq = 0; qq < 8; ++qq) {
        uint4 v = ((const uint4*)yb)[qq];
        unsigned uu[4] = {v.x, v.y, v.z, v.w};
#pragma unroll
        for (int r = 0; r < 4; ++r) {
            float f0 = __uint_as_float(uu[r] << 16);
            float f1 = __uint_as_float(uu[r] & 0xffff0000u);
            float v0 = fmaf(f0, A0, B0);
            v0 = v0 * __builtin_amdgcn_rcpf(1.0f + __expf(-v0));
            m0 = fmaxf(m0, v0);
            float v1 = fmaf(f1, A1, B1);
            v1 = v1 * __builtin_amdgcn_rcpf(1.0f + __expf(-v1));
            m1 = fmaxf(m1, v1);
        }
    }
    out[(size_t)(b * 128 + c0) * NC + s] = m0;
    out[(size_t)(b * 128 + c1) * NC + s] = m1;
}

// =====================================================================
extern "C" void kernel_launch(void* const* d_in, const int* in_sizes, int n_in,
                              void* d_out, int out_size, void* d_ws, size_t ws_size,
                              hipStream_t stream)
{
    if (ws_size < WS_NEEDED) return;

    const float* coords = (const float*)d_in[0];
    const float* feats  = (const float*)d_in[1];
    const float* w0  = (const float*)d_in[2];
    const float* b0  = (const float*)d_in[3];
    const float* g0  = (const float*)d_in[4];
    const float* be0 = (const float*)d_in[5];
    const float* w1  = (const float*)d_in[6];
    const float* b1  = (const float*)d_in[7];
    const float* g1  = (const float*)d_in[8];
    const float* be1 = (const float*)d_in[9];
    const float* w2  = (const float*)d_in[10];
    const float* b2  = (const float*)d_in[11];
    const float* g2  = (const float*)d_in[12];
    const float* be2 = (const float*)d_in[13];
    float* out = (float*)d_out;

    char* ws = (char*)d_ws;
    int*   cidx    = (int*)(ws + OFF_CIDX);
    int*   nidx    = (int*)(ws + OFF_NIDX);
    float* centers = (float*)(ws + OFF_CENT);
    float* statsP  = (float*)(ws + OFF_STATSP);   // [3][SBINS][128]
    float* statsF  = (float*)(ws + OFF_STATSF);   // [3][128]
    float* wt      = (float*)(ws + OFF_WT);
    float* xall    = (float*)(ws + OFF_XALL);
    float* Ybuf    = (float*)(ws + OFF_Y);

    prep_kernel<<<48, 256, 0, stream>>>(w0, w1, w2, statsP, statsF, wt);
    build_xall<<<(BATCH * NPTS) / 256, 256, 0, stream>>>(coords, feats, xall);
    // dynamic LDS: 3*NPTS floats (coords) + 8 u64 packs
    fps_kernel<<<BATCH, 256, 3 * NPTS * 4 + 64, stream>>>(coords, cidx);
    bq_kernel<<<dim3(NC, BATCH), 256, 0, stream>>>(coords, cidx, nidx, centers);

    const dim3 lgrid(NSCOL / 64, BATCH);
    l1_kernel<<<lgrid, 256, 0, stream>>>(xall, nidx, centers, wt, b0, Ybuf, statsP);
    reduce_stats<<<1, 128, 0, stream>>>(statsP, statsF);
    l2_kernel<<<lgrid, 256, 0, stream>>>(wt + 4288, b1, g0, be0,
                                         statsF, statsP + SBINS * 128, Ybuf);
    reduce_stats<<<1, 128, 0, stream>>>(statsP + SBINS * 128, statsF + 128);
    l3_kernel<<<lgrid, 256, 0, stream>>>(wt + 8384, b2, g1, be1,
                                         statsF + 128, statsP + 2 * SBINS * 128, Ybuf);
    reduce_stats<<<1, 128, 0, stream>>>(statsP + 2 * SBINS * 128, statsF + 256);
    fin_kernel<<<(BATCH * 64 * NC) / 256, 256, 0, stream>>>(
        (const unsigned*)Ybuf, g2, be2, statsF + 256, out);
    (void)in_sizes; (void)n_in; (void)out_size;
}